// Round 4
// baseline (606.239 us; speedup 1.0000x reference)
//
#include <hip/hip_runtime.h>
#include <math.h>

// Problem dims (fixed per reference): B=16, D=1024, DFF=4096, E=16, L=4.
//
// out[b] = (relu(x W1b^T + b1b)) W2b^T + b2b  where  Wib = bWi + sum_e c[b,e,l]*tvWi[e]
// Key identity: x·W1b[o,:] = x·bW1[o,:] + sum_e c[b,e,0]*(x·tvW1[e,o,:])
// -> tall-skinny GEMM over 69632 rows x K=1024 x 16 samples; tv read exactly once.

__device__ __forceinline__ float wave_reduce_to_lane(float (&acc)[64], const int lane) {
  // Merged tree reduce: after 6 stages, lane l holds the 64-lane sum of
  // original value index j == l.  63 shuffles + 63 adds total.
  #pragma unroll
  for (int k = 0; k < 6; ++k) {
    const int bit = (lane >> k) & 1;
    #pragma unroll
    for (int i = 0; i < (64 >> (k + 1)); ++i) {
      const float a  = acc[2 * i];
      const float bq = acc[2 * i + 1];
      const float mine = bit ? bq : a;   // data-select (cndmask), no runtime indexing
      const float send = bit ? a : bq;
      const float recv = __shfl_xor(send, 1 << k, 64);
      acc[i] = mine + recv;
    }
  }
  return acc[0];
}

#define ACCROW(R, AV)                                              \
  acc[(R)*16 + b] = fmaf((AV).x, xb.x, acc[(R)*16 + b]);           \
  acc[(R)*16 + b] = fmaf((AV).y, xb.y, acc[(R)*16 + b]);           \
  acc[(R)*16 + b] = fmaf((AV).z, xb.z, acc[(R)*16 + b]);           \
  acc[(R)*16 + b] = fmaf((AV).w, xb.w, acc[(R)*16 + b]);

// ---------- streaming merge GEMM: rows = [tv (16*O rows); base (O rows)] ----------
// atomicAdd(coef(b, ebar) * dot(row, X[b])) into out[b*O + o].
template<int K>
__global__ __launch_bounds__(256, 4)
void merge_gemm(const float* __restrict__ tv, const float* __restrict__ base,
                const float* __restrict__ X, const float* __restrict__ cod,
                const int lsel, float* __restrict__ out, const int O) {
  constexpr int CH = K / 256;
  __shared__ float xs[2][16][256];   // double-buffered X chunk, 32 KB
  const int tid  = threadIdx.x;
  const int lane = tid & 63;
  const int w    = tid >> 6;

  const int row0 = blockIdx.x * 16;        // 16 rows per block, never straddles experts
  const int ebar = row0 / O;               // 0..15 = tv expert, 16 = base (uniform in block)
  const int o0   = row0 - ebar * O;
  const float* mat = (ebar < 16) ? (tv + (size_t)ebar * O * K) : base;
  const int ow = o0 + w * 4;               // wave owns 4 consecutive rows
  const float* r0 = mat + (size_t)(ow + 0) * K + lane * 4;
  const float* r1 = mat + (size_t)(ow + 1) * K + lane * 4;
  const float* r2 = mat + (size_t)(ow + 2) * K + lane * 4;
  const float* r3 = mat + (size_t)(ow + 3) * K + lane * 4;

  float acc[64];
  #pragma unroll
  for (int i = 0; i < 64; ++i) acc[i] = 0.f;

  auto stage = [&](int c) {                // wave w stages sample rows {w,4+w,8+w,12+w}
    const int buf = c & 1;
    const int c0  = c * 256;
    #pragma unroll
    for (int k2 = 0; k2 < 4; ++k2) {
      const int b = 4 * k2 + w;
      const float4 v = *(const float4*)(X + (size_t)b * K + c0 + lane * 4);
      *(float4*)(&xs[buf][b][lane * 4]) = v;
    }
  };

  stage(0);
  __syncthreads();

  for (int c = 0; c < CH; ++c) {
    if (c + 1 < CH) stage(c + 1);
    const int cur = c & 1;
    const float4 a0 = *(const float4*)(r0 + (size_t)c * 256);
    const float4 a1 = *(const float4*)(r1 + (size_t)c * 256);
    const float4 a2 = *(const float4*)(r2 + (size_t)c * 256);
    const float4 a3 = *(const float4*)(r3 + (size_t)c * 256);
    #pragma unroll
    for (int b = 0; b < 16; ++b) {
      const float4 xb = *(const float4*)(&xs[cur][b][lane * 4]);
      ACCROW(0, a0) ACCROW(1, a1) ACCROW(2, a2) ACCROW(3, a3)
    }
    __syncthreads();
  }

  const float dot = wave_reduce_to_lane(acc, lane);
  const int r = lane >> 4;                 // which of the wave's 4 rows
  const int b = lane & 15;                 // which sample
  const int o = ow + r;
  const float coef = (ebar < 16) ? cod[b * 64 + ebar * 4 + lsel] : 1.0f;
  atomicAdd(&out[(size_t)b * O + o], coef * dot);
}

// ---------- gate GEMM (dense, bias, optional relu, direct store) ----------
template<int K, bool RELU>
__global__ __launch_bounds__(256, 4)
void gate_gemm(const float* __restrict__ W, const float* __restrict__ bias,
               const float* __restrict__ X, float* __restrict__ out, const int O) {
  constexpr int CH = K / 256;
  __shared__ float xs[2][16][256];
  const int tid  = threadIdx.x;
  const int lane = tid & 63;
  const int w    = tid >> 6;

  const int row0 = blockIdx.x * 16;
  const int ow   = row0 + w * 4;
  const float* r0 = W + (size_t)(ow + 0) * K + lane * 4;
  const float* r1 = W + (size_t)(ow + 1) * K + lane * 4;
  const float* r2 = W + (size_t)(ow + 2) * K + lane * 4;
  const float* r3 = W + (size_t)(ow + 3) * K + lane * 4;

  float acc[64];
  #pragma unroll
  for (int i = 0; i < 64; ++i) acc[i] = 0.f;

  auto stage = [&](int c) {
    const int buf = c & 1;
    const int c0  = c * 256;
    #pragma unroll
    for (int k2 = 0; k2 < 4; ++k2) {
      const int b = 4 * k2 + w;
      const float4 v = *(const float4*)(X + (size_t)b * K + c0 + lane * 4);
      *(float4*)(&xs[buf][b][lane * 4]) = v;
    }
  };

  stage(0);
  __syncthreads();

  for (int c = 0; c < CH; ++c) {
    if (c + 1 < CH) stage(c + 1);
    const int cur = c & 1;
    const float4 a0 = *(const float4*)(r0 + (size_t)c * 256);
    const float4 a1 = *(const float4*)(r1 + (size_t)c * 256);
    const float4 a2 = *(const float4*)(r2 + (size_t)c * 256);
    const float4 a3 = *(const float4*)(r3 + (size_t)c * 256);
    #pragma unroll
    for (int b = 0; b < 16; ++b) {
      const float4 xb = *(const float4*)(&xs[cur][b][lane * 4]);
      ACCROW(0, a0) ACCROW(1, a1) ACCROW(2, a2) ACCROW(3, a3)
    }
    __syncthreads();
  }

  const float dot = wave_reduce_to_lane(acc, lane);
  const int r = lane >> 4;
  const int b = lane & 15;
  const int o = ow + r;
  float v = dot + bias[o];
  if (RELU) v = fmaxf(v, 0.f);
  out[(size_t)b * O + o] = v;
}

// ---------- tiny epilogue/prologue kernels ----------
__global__ void init_bias_mix(const float* __restrict__ bb, const float* __restrict__ tvb,
                              const float* __restrict__ cod, const int lsel,
                              float* __restrict__ out, const int O) {
  const int t = blockIdx.x * 256 + threadIdx.x;   // t < 16*O
  const int b = t / O;
  const int o = t - b * O;
  float s = bb[o];
  #pragma unroll
  for (int e = 0; e < 16; ++e)
    s = fmaf(cod[b * 64 + e * 4 + lsel], tvb[e * O + o], s);
  out[t] = s;
}

__global__ void relu_kernel(const float* __restrict__ in, float* __restrict__ out, const int n) {
  const int t = blockIdx.x * 256 + threadIdx.x;
  if (t < n) out[t] = fmaxf(in[t], 0.f);
}

extern "C" void kernel_launch(void* const* d_in, const int* in_sizes, int n_in,
                              void* d_out, int out_size, void* d_ws, size_t ws_size,
                              hipStream_t stream) {
  (void)in_sizes; (void)n_in; (void)out_size; (void)ws_size;
  const float* x    = (const float*)d_in[0];
  const float* gW1  = (const float*)d_in[1];
  const float* gb1  = (const float*)d_in[2];
  const float* gW2  = (const float*)d_in[3];
  const float* gb2  = (const float*)d_in[4];
  const float* bW1  = (const float*)d_in[5];
  const float* bb1  = (const float*)d_in[6];
  const float* bW2  = (const float*)d_in[7];
  const float* bb2  = (const float*)d_in[8];
  const float* tvW1 = (const float*)d_in[9];
  const float* tvb1 = (const float*)d_in[10];
  const float* tvW2 = (const float*)d_in[11];
  const float* tvb2 = (const float*)d_in[12];
  float* out = (float*)d_out;

  // workspace layout (fp32): h[16*1024] | cod[16*64] | h1acc[16*4096] | h1[16*4096]
  float* h   = (float*)d_ws;
  float* cod = h   + 16 * 1024;
  float* h1a = cod + 16 * 64;
  float* h1  = h1a + 16 * 4096;

  dim3 blk(256);
  // gate: h = relu(x gW1^T + gb1); codings = h gW2^T + gb2
  gate_gemm<1024, true ><<<1024 / 16, blk, 0, stream>>>(gW1, gb1, x, h, 1024);
  gate_gemm<1024, false><<<64 / 16,   blk, 0, stream>>>(gW2, gb2, h, cod, 64);
  // layer 1: h1acc = bb1 + sum_e c[:,e,1] tvb1[e]  (init), then += merged matvec
  init_bias_mix<<<(16 * 4096) / 256, blk, 0, stream>>>(bb1, tvb1, cod, 1, h1a, 4096);
  merge_gemm<1024><<<(17 * 4096) / 16, blk, 0, stream>>>(tvW1, bW1, x, cod, 0, h1a, 4096);
  relu_kernel<<<(16 * 4096) / 256, blk, 0, stream>>>(h1a, h1, 16 * 4096);
  // layer 2: out = bb2 + sum_e c[:,e,3] tvb2[e], then += merged matvec on relu(h1)
  init_bias_mix<<<(16 * 1024) / 256, blk, 0, stream>>>(bb2, tvb2, cod, 3, out, 1024);
  merge_gemm<4096><<<(17 * 1024) / 16, blk, 0, stream>>>(tvW2, bW2, h1, cod, 2, out, 1024);
}

// Round 5
// 598.799 us; speedup vs baseline: 1.0124x; 1.0124x over previous
//
#include <hip/hip_runtime.h>
#include <math.h>

// Dims fixed per reference: B=16, D=1024, DFF=4096, E=16, L=4.
// out[b] = relu(x W1b^T + b1b) W2b^T + b2b,  Wib = bWi + sum_e c[b,e,l] tvWi[e]
// Merge trick: x·W1b[o,:] = x·bW1[o,:] + sum_e c[b,e,0] (x·tvW1[e,o,:])
// -> stream 69632 rows x K x 16 samples once; store raw dots to P[17][O][16];
//    gather kernel folds coefficients + bias-mix + relu. No atomics, no init.

__device__ __forceinline__ void gload_lds16(const float* g, float* lds_base) {
  // width-16 global->LDS DMA; dest = wave-uniform base + lane*16 (linear).
  __builtin_amdgcn_global_load_lds(
      (const __attribute__((address_space(1))) void*)g,
      (__attribute__((address_space(3))) void*)lds_base, 16, 0, 0);
}

__device__ __forceinline__ float wave_reduce_to_lane(float (&acc)[64], const int lane) {
  // Merged tree reduce: after 6 stages lane l holds the 64-lane sum of value l.
  #pragma unroll
  for (int k = 0; k < 6; ++k) {
    const int bit = (lane >> k) & 1;
    #pragma unroll
    for (int i = 0; i < (64 >> (k + 1)); ++i) {
      const float a  = acc[2 * i];
      const float bq = acc[2 * i + 1];
      const float mine = bit ? bq : a;
      const float send = bit ? a : bq;
      const float recv = __shfl_xor(send, 1 << k, 64);
      acc[i] = mine + recv;
    }
  }
  return acc[0];
}

#define ACCROW(R, AV)                                              \
  acc[(R)*16 + b] = fmaf((AV).x, xb.x, acc[(R)*16 + b]);           \
  acc[(R)*16 + b] = fmaf((AV).y, xb.y, acc[(R)*16 + b]);           \
  acc[(R)*16 + b] = fmaf((AV).z, xb.z, acc[(R)*16 + b]);           \
  acc[(R)*16 + b] = fmaf((AV).w, xb.w, acc[(R)*16 + b]);

// Shared K-loop: 16 matrix rows/block (wave w owns rows w*4..w*4+3, lane owns
// k-slice lane*4..lane*4+3 of each 256-float chunk), X[16][K] staged via
// global_load_lds double-buffer, next-chunk rows prefetched into regs.
template<int K>
__device__ __forceinline__ void run_kloop(const float* __restrict__ m0,
                                          const float* __restrict__ m1,
                                          const float* __restrict__ m2,
                                          const float* __restrict__ m3,
                                          const float* __restrict__ X,
                                          float (*xs)[16][256],  // [2][16][256]
                                          float (&acc)[64],
                                          const int lane, const int w) {
  constexpr int CH = K / 256;
  float4 acur[4], anxt[4];

  auto stage = [&](int c) {
    const int buf = c & 1;
    const int c0  = c * 256;
    #pragma unroll
    for (int k2 = 0; k2 < 4; ++k2) {
      const int b = 4 * k2 + w;                       // wave-uniform row
      gload_lds16(X + (size_t)b * K + c0 + lane * 4, &xs[buf][b][0]);
    }
  };
  auto loadrows = [&](int c, float4 (&a)[4]) {
    const int off = c * 256;
    a[0] = *(const float4*)(m0 + off);
    a[1] = *(const float4*)(m1 + off);
    a[2] = *(const float4*)(m2 + off);
    a[3] = *(const float4*)(m3 + off);
  };

  stage(0);
  loadrows(0, acur);
  __syncthreads();                                    // drains gll(0) via vmcnt(0)

  for (int c = 0; c < CH; ++c) {
    const int cur = c & 1;
    if (c + 1 < CH) {                                 // prefetch next chunk first
      stage(c + 1);                                   // -> other LDS buffer
      loadrows(c + 1, anxt);                          // -> regs, in flight over compute
    }
    #pragma unroll
    for (int b = 0; b < 16; ++b) {
      const float4 xb = *(const float4*)(&xs[cur][b][lane * 4]);
      ACCROW(0, acur[0]) ACCROW(1, acur[1]) ACCROW(2, acur[2]) ACCROW(3, acur[3])
    }
    if (c + 1 < CH) {
      #pragma unroll
      for (int i = 0; i < 4; ++i) acur[i] = anxt[i];
      __syncthreads();                                // uniform; next buf ready after
    }
  }
}

// rows = [tv (16*O rows); base (O rows)]; store raw dot to P[(ebar*O+o)*16+b].
template<int K>
__global__ __launch_bounds__(256, 4)
void merge_gemm(const float* __restrict__ tv, const float* __restrict__ base,
                const float* __restrict__ X, float* __restrict__ P, const int O) {
  __shared__ float xs[2][16][256];
  const int tid = threadIdx.x, lane = tid & 63, w = tid >> 6;
  const int row0 = blockIdx.x * 16;                   // never straddles experts
  const int ebar = row0 / O;                          // 0..15 tv, 16 base
  const int o0   = row0 - ebar * O;
  const float* mat = (ebar < 16) ? (tv + (size_t)ebar * O * K) : base;
  const int ow = o0 + w * 4;
  const float* m0 = mat + (size_t)(ow + 0) * K + lane * 4;
  const float* m1 = mat + (size_t)(ow + 1) * K + lane * 4;
  const float* m2 = mat + (size_t)(ow + 2) * K + lane * 4;
  const float* m3 = mat + (size_t)(ow + 3) * K + lane * 4;

  float acc[64];
  #pragma unroll
  for (int i = 0; i < 64; ++i) acc[i] = 0.f;

  run_kloop<K>(m0, m1, m2, m3, X, xs, acc, lane, w);

  const float dot = wave_reduce_to_lane(acc, lane);
  // lane = r*16+b maps to row ow+r, sample b -> contiguous 256 B per wave.
  P[(size_t)(ebar * O + ow) * 16 + lane] = dot;
}

// dense gate GEMM: out[b*O+o] = dot + bias, optional relu.
template<int K, bool RELU>
__global__ __launch_bounds__(256, 4)
void gate_gemm(const float* __restrict__ W, const float* __restrict__ bias,
               const float* __restrict__ X, float* __restrict__ out, const int O) {
  __shared__ float xs[2][16][256];
  const int tid = threadIdx.x, lane = tid & 63, w = tid >> 6;
  const int ow = blockIdx.x * 16 + w * 4;
  const float* m0 = W + (size_t)(ow + 0) * K + lane * 4;
  const float* m1 = W + (size_t)(ow + 1) * K + lane * 4;
  const float* m2 = W + (size_t)(ow + 2) * K + lane * 4;
  const float* m3 = W + (size_t)(ow + 3) * K + lane * 4;

  float acc[64];
  #pragma unroll
  for (int i = 0; i < 64; ++i) acc[i] = 0.f;

  run_kloop<K>(m0, m1, m2, m3, X, xs, acc, lane, w);

  const float dot = wave_reduce_to_lane(acc, lane);
  const int r = lane >> 4, b = lane & 15, o = ow + r;
  float v = dot + bias[o];
  if (RELU) v = fmaxf(v, 0.f);
  out[(size_t)b * O + o] = v;
}

// dst[b*O+o] = (relu?)( P[16][o][b] + bb[o] + sum_e c[b,e,lw] P[e][o][b]
//                                   + sum_e c[b,e,lb] tvb[e][o] )
template<int O, bool RELU>
__global__ void gather_mix(const float* __restrict__ P, const float* __restrict__ bb,
                           const float* __restrict__ tvb, const float* __restrict__ cod,
                           const int lw, const int lb, float* __restrict__ dst) {
  const int t = blockIdx.x * 256 + threadIdx.x;       // t = o*16 + b (coalesced P reads)
  const int o = t >> 4, b = t & 15;
  float s = P[(size_t)(16 * O + o) * 16 + b] + bb[o];
  #pragma unroll
  for (int e = 0; e < 16; ++e)
    s = fmaf(cod[b * 64 + e * 4 + lw], P[(size_t)(e * O + o) * 16 + b], s);
  #pragma unroll
  for (int e = 0; e < 16; ++e)
    s = fmaf(cod[b * 64 + e * 4 + lb], tvb[e * O + o], s);
  if (RELU) s = fmaxf(s, 0.f);
  dst[(size_t)b * O + o] = s;
}

extern "C" void kernel_launch(void* const* d_in, const int* in_sizes, int n_in,
                              void* d_out, int out_size, void* d_ws, size_t ws_size,
                              hipStream_t stream) {
  (void)in_sizes; (void)n_in; (void)out_size; (void)ws_size;
  const float* x    = (const float*)d_in[0];
  const float* gW1  = (const float*)d_in[1];
  const float* gb1  = (const float*)d_in[2];
  const float* gW2  = (const float*)d_in[3];
  const float* gb2  = (const float*)d_in[4];
  const float* bW1  = (const float*)d_in[5];
  const float* bb1  = (const float*)d_in[6];
  const float* bW2  = (const float*)d_in[7];
  const float* bb2  = (const float*)d_in[8];
  const float* tvW1 = (const float*)d_in[9];
  const float* tvb1 = (const float*)d_in[10];
  const float* tvW2 = (const float*)d_in[11];
  const float* tvb2 = (const float*)d_in[12];
  float* out = (float*)d_out;

  // ws (fp32): h[16*1024] | cod[16*64] | P1[17*4096*16] | h1[16*4096] | P2[17*1024*16]
  float* h   = (float*)d_ws;
  float* cod = h   + 16 * 1024;
  float* P1  = cod + 16 * 64;
  float* h1  = P1  + 17 * 4096 * 16;
  float* P2  = h1  + 16 * 4096;

  dim3 blk(256);
  gate_gemm<1024, true ><<<64, blk, 0, stream>>>(gW1, gb1, x, h, 1024);
  gate_gemm<1024, false><<<4,  blk, 0, stream>>>(gW2, gb2, h, cod, 64);
  merge_gemm<1024><<<17 * 4096 / 16, blk, 0, stream>>>(tvW1, bW1, x, P1, 4096);
  gather_mix<4096, true ><<<16 * 4096 / 256, blk, 0, stream>>>(P1, bb1, tvb1, cod, 0, 1, h1);
  merge_gemm<4096><<<17 * 1024 / 16, blk, 0, stream>>>(tvW2, bW2, h1, P2, 1024);
  gather_mix<1024, false><<<16 * 1024 / 256, blk, 0, stream>>>(P2, bb2, tvb2, cod, 2, 3, out);
}